// Round 10
// baseline (435.155 us; speedup 1.0000x reference)
//
#include <hip/hip_runtime.h>

// DigitCapsules dynamic routing. Round-10 = Round-9 with the compile fix:
// __builtin_nontemporal_load needs a native clang vector type, not
// HIP_vector_type. W rows now flow as u4 (ext_vector_type(4) unsigned).
//
// Design recap (R9):
//  - R8 measured time ~ linear in W class-sweeps, TLP-flat => per-CU memory
//    pipe bound, ~11.8 us per class-sweep. Lever: sweep count.
//  - u_hat cached ACROSS iterations: classes 0..4 in registers (120 VGPRs,
//    static indexing), classes 5..7 in LDS f16 (110.6 KB), classes 8..9
//    recomputed. Class-sweeps 30 -> 14.
//  - it=0: softmax(0)=0.1 exactly -> skip softmax, scale s by 0.1, first
//    agreement WRITES blog.
//  - One barrier per class: parity-double-buffered red, redundant per-wave
//    squash, wave 0 writes out.
//  - Proven: TPB=512 launch_bounds(512,1) (cap 256), blog LDS BPAD=11
//    (0 conflicts in R8), f16 Wt[c][d][i] + v_dot2_f32_f16.

#define NCLS   10
#define NCAPS  1152
#define KDO    16
#define NIT    3
#define TPB    512
#define NJ     3            // j=0,1 all threads; j=2 only t<128
#define NWAVE  (TPB / 64)
#define BPAD   11
#define NC_REG 5            // classes 0..4 cached in registers
#define NC_LDS 3            // classes 5..7 cached in LDS (f16)

typedef _Float16 h2_t __attribute__((ext_vector_type(2)));
typedef unsigned u4 __attribute__((ext_vector_type(4)));   // nontemporal-load-able

static __device__ __forceinline__ unsigned pack2h(float a, float b) {
    union { _Float16 h[2]; unsigned u; } p;
    p.h[0] = (_Float16)a;
    p.h[1] = (_Float16)b;
    return p.u;
}

static __device__ __forceinline__ float dot8h(u4 r, const unsigned* xh) {
    union { unsigned u; h2_t h; } w0, w1, w2, w3, a0, a1, a2, a3;
    w0.u = r.x; w1.u = r.y; w2.u = r.z; w3.u = r.w;
    a0.u = xh[0]; a1.u = xh[1]; a2.u = xh[2]; a3.u = xh[3];
#if __has_builtin(__builtin_amdgcn_fdot2)
    float acc = __builtin_amdgcn_fdot2(w0.h, a0.h, 0.f, false);
    acc = __builtin_amdgcn_fdot2(w1.h, a1.h, acc, false);
    acc = __builtin_amdgcn_fdot2(w2.h, a2.h, acc, false);
    acc = __builtin_amdgcn_fdot2(w3.h, a3.h, acc, false);
    return acc;
#else
    return (float)w0.h.x * (float)a0.h.x + (float)w0.h.y * (float)a0.h.y
         + (float)w1.h.x * (float)a1.h.x + (float)w1.h.y * (float)a1.h.y
         + (float)w2.h.x * (float)a2.h.x + (float)w2.h.y * (float)a2.h.y
         + (float)w3.h.x * (float)a3.h.x + (float)w3.h.y * (float)a3.h.y;
#endif
}

static __device__ __forceinline__ float dot2h(unsigned a, unsigned b, float acc) {
    union { unsigned u; h2_t h; } pa, pb;
    pa.u = a; pb.u = b;
#if __has_builtin(__builtin_amdgcn_fdot2)
    return __builtin_amdgcn_fdot2(pa.h, pb.h, acc, false);
#else
    return acc + (float)pa.h.x * (float)pb.h.x + (float)pa.h.y * (float)pb.h.y;
#endif
}

// Wt[c][d][i] : u4 holding f16 W[c,i,0,d,k] for k=0..7
__global__ __launch_bounds__(256)
void pack_W_f16(const float4* __restrict__ W4, u4* __restrict__ Wt) {
    int tid = blockIdx.x * blockDim.x + threadIdx.x;   // (c*NCAPS+i)*KDO + d
    if (tid >= NCLS * NCAPS * KDO) return;
    int d = tid & 15;
    int rest = tid >> 4;
    int i = rest % NCAPS;
    int c = rest / NCAPS;
    float4 a = W4[2 * tid];
    float4 b = W4[2 * tid + 1];
    u4 o;
    o.x = pack2h(a.x, a.y);
    o.y = pack2h(a.z, a.w);
    o.z = pack2h(b.x, b.y);
    o.w = pack2h(b.z, b.w);
    Wt[(size_t)(c * KDO + d) * NCAPS + i] = o;
}

// ---- sweep one class's W: u into up[][] (packed f16), weighted into acc ----
static __device__ __forceinline__ void sweep_class(
        const u4* __restrict__ Wt, int c, const unsigned (&xh)[NJ][4],
        int t, const float (&wj)[NJ], unsigned (&up)[NJ][8], float (&acc)[KDO])
{
    #pragma unroll
    for (int j = 0; j < NJ; ++j) {
        int ii = t + TPB * j;
        if (ii < NCAPS) {
            const u4* base = Wt + (size_t)c * KDO * NCAPS + ii;
            #pragma unroll
            for (int dp = 0; dp < 8; ++dp) {
                u4 r0 = __builtin_nontemporal_load(base + (size_t)(2 * dp) * NCAPS);
                u4 r1 = __builtin_nontemporal_load(base + (size_t)(2 * dp + 1) * NCAPS);
                float u0 = dot8h(r0, xh[j]);
                float u1 = dot8h(r1, xh[j]);
                acc[2 * dp]     += wj[j] * u0;
                acc[2 * dp + 1] += wj[j] * u1;
                up[j][dp] = pack2h(u0, u1);
            }
        }
    }
}

// ---- weighted accumulate from cached packed-f16 u ----
static __device__ __forceinline__ void acc_from_u(
        const unsigned (&up)[NJ][8], const float (&wj)[NJ], int t, float (&acc)[KDO])
{
    #pragma unroll
    for (int j = 0; j < NJ; ++j) {
        int ii = t + TPB * j;
        if (ii < NCAPS) {
            #pragma unroll
            for (int dp = 0; dp < 8; ++dp) {
                union { unsigned u; h2_t h; } p; p.u = up[j][dp];
                acc[2 * dp]     += wj[j] * (float)p.h.x;
                acc[2 * dp + 1] += wj[j] * (float)p.h.y;
            }
        }
    }
}

// ---- reduce + squash + (out-write | agreement). ONE barrier, red parity. ----
static __device__ __forceinline__ void class_tail(
        int c, bool last, bool first, float s_scale,
        int t, int lane, int wave, int par,
        const unsigned (&up)[NJ][8], float (&acc)[KDO],
        float* __restrict__ blogL, float (*__restrict__ red)[NWAVE * KDO],
        float* __restrict__ outb)
{
    #pragma unroll
    for (int d = 0; d < KDO; ++d) {
        float v = acc[d];
        v += __shfl_xor(v, 32, 64);
        v += __shfl_xor(v, 16, 64);
        v += __shfl_xor(v,  8, 64);
        v += __shfl_xor(v,  4, 64);
        v += __shfl_xor(v,  2, 64);
        v += __shfl_xor(v,  1, 64);
        if (lane == 0) red[par][wave * KDO + d] = v;
    }
    __syncthreads();

    // every wave redundantly computes s, v (lanes: d = lane&15, 4 replicas)
    int dl = lane & 15;
    float s = 0.f;
    #pragma unroll
    for (int w = 0; w < NWAVE; ++w) s += red[par][w * KDO + dl];
    s *= s_scale;
    float nsq = s * s;
    nsq += __shfl_xor(nsq, 8, 16);
    nsq += __shfl_xor(nsq, 4, 16);
    nsq += __shfl_xor(nsq, 2, 16);
    nsq += __shfl_xor(nsq, 1, 16);
    float sc = sqrtf(nsq) / (1.f + nsq);       // (nsq/(1+nsq))/sqrt(nsq)
    float vv = s * sc;

    if (last) {
        if (wave == 0 && lane < 16)
            outb[c * KDO + lane] = vv;
    } else {
        unsigned vp[8];
        #pragma unroll
        for (int dp = 0; dp < 8; ++dp) {
            float a = __shfl(vv, (lane & 48) + 2 * dp, 64);
            float b = __shfl(vv, (lane & 48) + 2 * dp + 1, 64);
            vp[dp] = pack2h(a, b);
        }
        #pragma unroll
        for (int j = 0; j < NJ; ++j) {
            int ii = t + TPB * j;
            if (ii < NCAPS) {
                float a = 0.f;
                #pragma unroll
                for (int dp = 0; dp < 8; ++dp) a = dot2h(up[j][dp], vp[dp], a);
                if (first) blogL[ii * BPAD + c] = a;     // it0: first write, no init
                else       blogL[ii * BPAD + c] += a;
            }
        }
    }
}

__global__ __launch_bounds__(TPB, 1)          // cap = 256 VGPR (R8-verified)
void caps_routing_v9(const u4* __restrict__ Wt,    // [C][KDO][I] f16x8
                     const float* __restrict__ x,  // [B, I, 8]
                     float* __restrict__ out)      // [B, C, 1, KDO]
{
    const int b    = blockIdx.x;
    const int t    = threadIdx.x;
    const int lane = t & 63;
    const int wave = t >> 6;

    __shared__ float blogL[NCAPS * BPAD];               // 50688 B
    __shared__ u4 ucache[NC_LDS * NCAPS * 2];           // 110592 B (u f16, 3 cls)
    __shared__ float red[2][NWAVE * KDO];               // 1024 B  -> 162304 total

    // ---- x[b, ii, :] packed f16 in registers ----
    unsigned xh[NJ][4];
    const float4* x4 = reinterpret_cast<const float4*>(x) + (size_t)b * NCAPS * 2;
    #pragma unroll
    for (int j = 0; j < NJ; ++j) {
        int ii = t + TPB * j;
        if (ii < NCAPS) {
            float4 x0 = x4[2 * ii];
            float4 x1 = x4[2 * ii + 1];
            xh[j][0] = pack2h(x0.x, x0.y);
            xh[j][1] = pack2h(x0.z, x0.w);
            xh[j][2] = pack2h(x1.x, x1.y);
            xh[j][3] = pack2h(x1.z, x1.w);
        }
    }

    float* outb = out + (size_t)b * NCLS * KDO;
    unsigned upk[NC_REG][NJ][8];                        // 120 VGPRs, static idx only
    int par = 0;

    // ================= it = 0 : softmax(0)=0.1 -> unweighted, scale 0.1 =====
    {
        float w1[NJ];
        #pragma unroll
        for (int j = 0; j < NJ; ++j) w1[j] = 1.f;

        #pragma unroll
        for (int c = 0; c < NC_REG; ++c) {              // register-cached classes
            float acc[KDO];
            #pragma unroll
            for (int d = 0; d < KDO; ++d) acc[d] = 0.f;
            sweep_class(Wt, c, xh, t, w1, upk[c], acc);
            class_tail(c, false, true, 0.1f, t, lane, wave, par, upk[c], acc,
                       blogL, red, outb);
            par ^= 1;
        }
        #pragma unroll 1
        for (int cc = 0; cc < NC_LDS; ++cc) {           // LDS-cached classes
            int c = NC_REG + cc;
            unsigned up[NJ][8];
            float acc[KDO];
            #pragma unroll
            for (int d = 0; d < KDO; ++d) acc[d] = 0.f;
            sweep_class(Wt, c, xh, t, w1, up, acc);
            #pragma unroll
            for (int j = 0; j < NJ; ++j) {
                int ii = t + TPB * j;
                if (ii < NCAPS) {
                    u4 h0, h1;
                    h0.x = up[j][0]; h0.y = up[j][1]; h0.z = up[j][2]; h0.w = up[j][3];
                    h1.x = up[j][4]; h1.y = up[j][5]; h1.z = up[j][6]; h1.w = up[j][7];
                    ucache[(cc * NCAPS + ii) * 2 + 0] = h0;
                    ucache[(cc * NCAPS + ii) * 2 + 1] = h1;
                }
            }
            class_tail(c, false, true, 0.1f, t, lane, wave, par, up, acc,
                       blogL, red, outb);
            par ^= 1;
        }
        #pragma unroll 1
        for (int c = NC_REG + NC_LDS; c < NCLS; ++c) {  // recomputed classes
            unsigned up[NJ][8];
            float acc[KDO];
            #pragma unroll
            for (int d = 0; d < KDO; ++d) acc[d] = 0.f;
            sweep_class(Wt, c, xh, t, w1, up, acc);
            class_tail(c, false, true, 0.1f, t, lane, wave, par, up, acc,
                       blogL, red, outb);
            par ^= 1;
        }
    }

    // ================= it = 1, 2 ===========================================
    #pragma unroll 1
    for (int it = 1; it < NIT; ++it) {
        bool last = (it == NIT - 1);

        // softmax over classes per capsule (thread-private blog slots)
        float sm[NJ], sid[NJ];
        #pragma unroll
        for (int j = 0; j < NJ; ++j) {
            int ii = t + TPB * j;
            if (ii < NCAPS) {
                float bl[NCLS];
                #pragma unroll
                for (int c = 0; c < NCLS; ++c) bl[c] = blogL[ii * BPAD + c];
                float m = bl[0];
                #pragma unroll
                for (int c = 1; c < NCLS; ++c) m = fmaxf(m, bl[c]);
                float den = 0.f;
                #pragma unroll
                for (int c = 0; c < NCLS; ++c) den += __expf(bl[c] - m);
                sm[j]  = m;
                sid[j] = 1.f / den;
            }
        }

        #pragma unroll
        for (int c = 0; c < NC_REG; ++c) {              // from registers: no loads
            float wj[NJ];
            #pragma unroll
            for (int j = 0; j < NJ; ++j) {
                int ii = t + TPB * j;
                wj[j] = (ii < NCAPS) ? __expf(blogL[ii * BPAD + c] - sm[j]) * sid[j] : 0.f;
            }
            float acc[KDO];
            #pragma unroll
            for (int d = 0; d < KDO; ++d) acc[d] = 0.f;
            acc_from_u(upk[c], wj, t, acc);
            class_tail(c, last, false, 1.f, t, lane, wave, par, upk[c], acc,
                       blogL, red, outb);
            par ^= 1;
        }
        #pragma unroll 1
        for (int cc = 0; cc < NC_LDS; ++cc) {           // from LDS: ds_read only
            int c = NC_REG + cc;
            unsigned up[NJ][8];
            #pragma unroll
            for (int j = 0; j < NJ; ++j) {
                int ii = t + TPB * j;
                if (ii < NCAPS) {
                    u4 h0 = ucache[(cc * NCAPS + ii) * 2 + 0];
                    u4 h1 = ucache[(cc * NCAPS + ii) * 2 + 1];
                    up[j][0] = h0.x; up[j][1] = h0.y; up[j][2] = h0.z; up[j][3] = h0.w;
                    up[j][4] = h1.x; up[j][5] = h1.y; up[j][6] = h1.z; up[j][7] = h1.w;
                }
            }
            float wj[NJ];
            #pragma unroll
            for (int j = 0; j < NJ; ++j) {
                int ii = t + TPB * j;
                wj[j] = (ii < NCAPS) ? __expf(blogL[ii * BPAD + c] - sm[j]) * sid[j] : 0.f;
            }
            float acc[KDO];
            #pragma unroll
            for (int d = 0; d < KDO; ++d) acc[d] = 0.f;
            acc_from_u(up, wj, t, acc);
            class_tail(c, last, false, 1.f, t, lane, wave, par, up, acc,
                       blogL, red, outb);
            par ^= 1;
        }
        #pragma unroll 1
        for (int c = NC_REG + NC_LDS; c < NCLS; ++c) {  // recompute: W sweep
            float wj[NJ];
            #pragma unroll
            for (int j = 0; j < NJ; ++j) {
                int ii = t + TPB * j;
                wj[j] = (ii < NCAPS) ? __expf(blogL[ii * BPAD + c] - sm[j]) * sid[j] : 0.f;
            }
            unsigned up[NJ][8];
            float acc[KDO];
            #pragma unroll
            for (int d = 0; d < KDO; ++d) acc[d] = 0.f;
            sweep_class(Wt, c, xh, t, wj, up, acc);
            class_tail(c, last, false, 1.f, t, lane, wave, par, up, acc,
                       blogL, red, outb);
            par ^= 1;
        }
    }
}

// ---- fallback (no workspace): round-1 fp32 kernel, proven correct ----
__global__ __launch_bounds__(256, 2)
void caps_routing_fb(const float* __restrict__ x, const float* __restrict__ W,
                     float* __restrict__ out)
{
    const int b    = blockIdx.x;
    const int t    = threadIdx.x;
    const int lane = t & 63;
    const int wave = t >> 6;
    __shared__ float v_prev[NCLS * KDO];
    __shared__ float redf[NCLS * 4 * KDO];
    float4 xr[5][2];
    const float4* x4 = reinterpret_cast<const float4*>(x + (size_t)b * NCAPS * 8);
    #pragma unroll
    for (int j = 0; j < 5; ++j) {
        int i = t + 256 * j;
        if (i < NCAPS) { xr[j][0] = x4[2 * i]; xr[j][1] = x4[2 * i + 1]; }
    }
    float blog[5][NCLS];
    #pragma unroll
    for (int j = 0; j < 5; ++j)
        #pragma unroll
        for (int c = 0; c < NCLS; ++c) blog[j][c] = 0.f;
    const float4* W4 = reinterpret_cast<const float4*>(W);
    for (int it = 0; it < NIT; ++it) {
        if (it > 0) {
            for (int c = 0; c < NCLS; ++c) {
                float vp[KDO];
                #pragma unroll
                for (int d = 0; d < KDO; ++d) vp[d] = v_prev[c * KDO + d];
                #pragma unroll
                for (int j = 0; j < 5; ++j) {
                    int i = t + 256 * j;
                    if (i < NCAPS) {
                        size_t wb = (size_t)(c * NCAPS + i) * 32;
                        float a = 0.f;
                        #pragma unroll
                        for (int d = 0; d < KDO; ++d) {
                            float4 w0 = W4[wb + 2 * d]; float4 w1 = W4[wb + 2 * d + 1];
                            float u = w0.x*xr[j][0].x + w0.y*xr[j][0].y + w0.z*xr[j][0].z
                                    + w0.w*xr[j][0].w + w1.x*xr[j][1].x + w1.y*xr[j][1].y
                                    + w1.z*xr[j][1].z + w1.w*xr[j][1].w;
                            a += u * vp[d];
                        }
                        blog[j][c] += a;
                    }
                }
            }
        }
        float sm[5], sid[5];
        #pragma unroll
        for (int j = 0; j < 5; ++j) {
            int i = t + 256 * j;
            if (i < NCAPS) {
                float m = blog[j][0];
                #pragma unroll
                for (int c = 1; c < NCLS; ++c) m = fmaxf(m, blog[j][c]);
                float den = 0.f;
                #pragma unroll
                for (int c = 0; c < NCLS; ++c) den += __expf(blog[j][c] - m);
                sm[j] = m; sid[j] = 1.f / den;
            }
        }
        for (int c = 0; c < NCLS; ++c) {
            float acc[KDO];
            #pragma unroll
            for (int d = 0; d < KDO; ++d) acc[d] = 0.f;
            #pragma unroll
            for (int j = 0; j < 5; ++j) {
                int i = t + 256 * j;
                if (i < NCAPS) {
                    float w = __expf(blog[j][c] - sm[j]) * sid[j];
                    size_t wb = (size_t)(c * NCAPS + i) * 32;
                    #pragma unroll
                    for (int d = 0; d < KDO; ++d) {
                        float4 w0 = W4[wb + 2 * d]; float4 w1 = W4[wb + 2 * d + 1];
                        float u = w0.x*xr[j][0].x + w0.y*xr[j][0].y + w0.z*xr[j][0].z
                                + w0.w*xr[j][0].w + w1.x*xr[j][1].x + w1.y*xr[j][1].y
                                + w1.z*xr[j][1].z + w1.w*xr[j][1].w;
                        acc[d] += w * u;
                    }
                }
            }
            #pragma unroll
            for (int d = 0; d < KDO; ++d) {
                float v = acc[d];
                v += __shfl_xor(v, 32, 64); v += __shfl_xor(v, 16, 64);
                v += __shfl_xor(v,  8, 64); v += __shfl_xor(v,  4, 64);
                v += __shfl_xor(v,  2, 64); v += __shfl_xor(v,  1, 64);
                if (lane == 0) redf[(c * 4 + wave) * KDO + d] = v;
            }
        }
        __syncthreads();
        if (t < NCLS * KDO) {
            int c = t >> 4, d = t & 15;
            float s = redf[(c*4+0)*KDO+d] + redf[(c*4+1)*KDO+d]
                    + redf[(c*4+2)*KDO+d] + redf[(c*4+3)*KDO+d];
            float nsq = s * s;
            nsq += __shfl_xor(nsq, 8, 16); nsq += __shfl_xor(nsq, 4, 16);
            nsq += __shfl_xor(nsq, 2, 16); nsq += __shfl_xor(nsq, 1, 16);
            float scale = sqrtf(nsq) / (1.f + nsq);
            float vv = s * scale;
            v_prev[t] = vv;
            if (it == NIT - 1) out[(size_t)b * NCLS * KDO + t] = vv;
        }
        __syncthreads();
    }
}

extern "C" void kernel_launch(void* const* d_in, const int* in_sizes, int n_in,
                              void* d_out, int out_size, void* d_ws, size_t ws_size,
                              hipStream_t stream) {
    const float* x = (const float*)d_in[0];              // [256, 1152, 8] fp32
    const float4* W4 = (const float4*)d_in[1];           // [10, 1152, 1, 16, 8] fp32
    float* out = (float*)d_out;                          // [256, 10, 1, 16] fp32
    (void)in_sizes; (void)n_in; (void)out_size;

    const int B = 256;
    const size_t wt_bytes = (size_t)NCLS * KDO * NCAPS * sizeof(u4);  // 2.95 MB
    if (ws_size >= wt_bytes) {
        u4* Wt = (u4*)d_ws;
        int total = NCLS * NCAPS * KDO;
        pack_W_f16<<<dim3((total + 255) / 256), dim3(256), 0, stream>>>(W4, Wt);
        caps_routing_v9<<<dim3(B), dim3(TPB), 0, stream>>>(Wt, x, out);
    } else {
        caps_routing_fb<<<dim3(B), dim3(256), 0, stream>>>(x, (const float*)d_in[1], out);
    }
}

// Round 11
// 347.350 us; speedup vs baseline: 1.2528x; 1.2528x over previous
//
#include <hip/hip_runtime.h>

// DigitCapsules dynamic routing. Round-11 design:
//  - R10 post-mortem: per-class-pass cost (~11.8 us) is NOT W-byte-bound
//    (one class-sweep is only 0.29 MB/CU => ~10 B/cyc effective - glacial).
//    R7 (72 loads/pass) and R8 (36 loads/pass) cost the same per pass =>
//    passes are LOAD-LATENCY-SERIALIZED: compiler emits load-pair ->
//    waitcnt -> consume per dp step, ~225 cyc L2 latency every 2 loads.
//  - FIX: batch all 16 W-row loads of a (class, j) chunk into u4 r[16]
//    BEFORE any consumption -> 16 loads in flight, latency amortized 8x.
//  - All u-caching dropped (R10: caching sweeps didn't pay; register cache
//    spilled at TPB=512's measured 128-VGPR cap; ucache had 442K bank
//    conflicts). Back to R8's clean 30-pass skeleton + R10's 1-barrier tail.
//  - TPB=256, __launch_bounds__(256,1): measured VGPR cap 256 (R6). Peak
//    live regs ~170 (r[16]=64 + up=40 + xh=20 + acc=16 + misc) - fits.
//  - Kept proven: blog in LDS (BPAD=11, 0 conflicts), f16 Wt[c][d][i] +
//    v_dot2_f32_f16, it0 softmax(0)=0.1 shortcut, parity-red 1-barrier tail.

#define NCLS   10
#define NCAPS  1152
#define KDO    16
#define NIT    3
#define TPB    256
#define NJ     5            // j=0..3 all threads; j=4 only t<128
#define NWAVE  (TPB / 64)
#define BPAD   11

typedef _Float16 h2_t __attribute__((ext_vector_type(2)));
typedef unsigned u4 __attribute__((ext_vector_type(4)));   // nontemporal-load-able

static __device__ __forceinline__ unsigned pack2h(float a, float b) {
    union { _Float16 h[2]; unsigned u; } p;
    p.h[0] = (_Float16)a;
    p.h[1] = (_Float16)b;
    return p.u;
}

static __device__ __forceinline__ float dot8h(u4 r, const unsigned* xh) {
    union { unsigned u; h2_t h; } w0, w1, w2, w3, a0, a1, a2, a3;
    w0.u = r.x; w1.u = r.y; w2.u = r.z; w3.u = r.w;
    a0.u = xh[0]; a1.u = xh[1]; a2.u = xh[2]; a3.u = xh[3];
#if __has_builtin(__builtin_amdgcn_fdot2)
    float acc = __builtin_amdgcn_fdot2(w0.h, a0.h, 0.f, false);
    acc = __builtin_amdgcn_fdot2(w1.h, a1.h, acc, false);
    acc = __builtin_amdgcn_fdot2(w2.h, a2.h, acc, false);
    acc = __builtin_amdgcn_fdot2(w3.h, a3.h, acc, false);
    return acc;
#else
    return (float)w0.h.x * (float)a0.h.x + (float)w0.h.y * (float)a0.h.y
         + (float)w1.h.x * (float)a1.h.x + (float)w1.h.y * (float)a1.h.y
         + (float)w2.h.x * (float)a2.h.x + (float)w2.h.y * (float)a2.h.y
         + (float)w3.h.x * (float)a3.h.x + (float)w3.h.y * (float)a3.h.y;
#endif
}

static __device__ __forceinline__ float dot2h(unsigned a, unsigned b, float acc) {
    union { unsigned u; h2_t h; } pa, pb;
    pa.u = a; pb.u = b;
#if __has_builtin(__builtin_amdgcn_fdot2)
    return __builtin_amdgcn_fdot2(pa.h, pb.h, acc, false);
#else
    return acc + (float)pa.h.x * (float)pb.h.x + (float)pa.h.y * (float)pb.h.y;
#endif
}

// Wt[c][d][i] : u4 holding f16 W[c,i,0,d,k] for k=0..7
__global__ __launch_bounds__(256)
void pack_W_f16(const float4* __restrict__ W4, u4* __restrict__ Wt) {
    int tid = blockIdx.x * blockDim.x + threadIdx.x;   // (c*NCAPS+i)*KDO + d
    if (tid >= NCLS * NCAPS * KDO) return;
    int d = tid & 15;
    int rest = tid >> 4;
    int i = rest % NCAPS;
    int c = rest / NCAPS;
    float4 a = W4[2 * tid];
    float4 b = W4[2 * tid + 1];
    u4 o;
    o.x = pack2h(a.x, a.y);
    o.y = pack2h(a.z, a.w);
    o.z = pack2h(b.x, b.y);
    o.w = pack2h(b.z, b.w);
    Wt[(size_t)(c * KDO + d) * NCAPS + i] = o;
}

// ---- one class-sweep: BATCHED 16-row load, then dots. up = packed u_hat. ----
static __device__ __forceinline__ void sweep_class(
        const u4* __restrict__ Wt, int c, const unsigned (&xh)[NJ][4],
        int t, const float (&wj)[NJ], unsigned (&up)[NJ][8], float (&acc)[KDO])
{
    #pragma unroll
    for (int j = 0; j < NJ; ++j) {
        int ii = t + TPB * j;
        if (ii < NCAPS) {
            const u4* base = Wt + (size_t)c * KDO * NCAPS + ii;
            u4 r[KDO];                           // 64 VGPRs, all loads in flight
            #pragma unroll
            for (int d = 0; d < KDO; ++d)
                r[d] = __builtin_nontemporal_load(base + (size_t)d * NCAPS);
            #pragma unroll
            for (int dp = 0; dp < 8; ++dp) {
                float u0 = dot8h(r[2 * dp],     xh[j]);
                float u1 = dot8h(r[2 * dp + 1], xh[j]);
                acc[2 * dp]     += wj[j] * u0;
                acc[2 * dp + 1] += wj[j] * u1;
                up[j][dp] = pack2h(u0, u1);
            }
        }
    }
}

// ---- reduce + squash + (out-write | agreement). ONE barrier, red parity. ----
static __device__ __forceinline__ void class_tail(
        int c, bool last, bool first, float s_scale,
        int t, int lane, int wave, int par,
        const unsigned (&up)[NJ][8], float (&acc)[KDO],
        float* __restrict__ blogL, float (*__restrict__ red)[NWAVE * KDO],
        float* __restrict__ outb)
{
    #pragma unroll
    for (int d = 0; d < KDO; ++d) {
        float v = acc[d];
        v += __shfl_xor(v, 32, 64);
        v += __shfl_xor(v, 16, 64);
        v += __shfl_xor(v,  8, 64);
        v += __shfl_xor(v,  4, 64);
        v += __shfl_xor(v,  2, 64);
        v += __shfl_xor(v,  1, 64);
        if (lane == 0) red[par][wave * KDO + d] = v;
    }
    __syncthreads();

    // every wave redundantly computes s, v (lanes: d = lane&15, 4 replicas)
    int dl = lane & 15;
    float s = 0.f;
    #pragma unroll
    for (int w = 0; w < NWAVE; ++w) s += red[par][w * KDO + dl];
    s *= s_scale;
    float nsq = s * s;
    nsq += __shfl_xor(nsq, 8, 16);
    nsq += __shfl_xor(nsq, 4, 16);
    nsq += __shfl_xor(nsq, 2, 16);
    nsq += __shfl_xor(nsq, 1, 16);
    float sc = sqrtf(nsq) / (1.f + nsq);       // (nsq/(1+nsq))/sqrt(nsq)
    float vv = s * sc;

    if (last) {
        if (wave == 0 && lane < 16)
            outb[c * KDO + lane] = vv;
    } else {
        unsigned vp[8];
        #pragma unroll
        for (int dp = 0; dp < 8; ++dp) {
            float a = __shfl(vv, (lane & 48) + 2 * dp, 64);
            float b = __shfl(vv, (lane & 48) + 2 * dp + 1, 64);
            vp[dp] = pack2h(a, b);
        }
        #pragma unroll
        for (int j = 0; j < NJ; ++j) {
            int ii = t + TPB * j;
            if (ii < NCAPS) {
                float a = 0.f;
                #pragma unroll
                for (int dp = 0; dp < 8; ++dp) a = dot2h(up[j][dp], vp[dp], a);
                if (first) blogL[ii * BPAD + c] = a;     // it0: first write, no init
                else       blogL[ii * BPAD + c] += a;
            }
        }
    }
}

__global__ __launch_bounds__(TPB, 1)          // cap 256 VGPR at TPB=256 (R6-measured)
void caps_routing_v11(const u4* __restrict__ Wt,    // [C][KDO][I] f16x8
                      const float* __restrict__ x,  // [B, I, 8]
                      float* __restrict__ out)      // [B, C, 1, KDO]
{
    const int b    = blockIdx.x;
    const int t    = threadIdx.x;
    const int lane = t & 63;
    const int wave = t >> 6;

    __shared__ float blogL[NCAPS * BPAD];               // 50688 B
    __shared__ float red[2][NWAVE * KDO];               // 512 B

    // ---- x[b, ii, :] packed f16 in registers ----
    unsigned xh[NJ][4];
    const float4* x4 = reinterpret_cast<const float4*>(x) + (size_t)b * NCAPS * 2;
    #pragma unroll
    for (int j = 0; j < NJ; ++j) {
        int ii = t + TPB * j;
        if (ii < NCAPS) {
            float4 x0 = x4[2 * ii];
            float4 x1 = x4[2 * ii + 1];
            xh[j][0] = pack2h(x0.x, x0.y);
            xh[j][1] = pack2h(x0.z, x0.w);
            xh[j][2] = pack2h(x1.x, x1.y);
            xh[j][3] = pack2h(x1.z, x1.w);
        }
    }

    float* outb = out + (size_t)b * NCLS * KDO;
    int par = 0;

    // ================= it = 0 : softmax(0)=0.1 -> unweighted, scale 0.1 =====
    {
        float w1[NJ];
        #pragma unroll
        for (int j = 0; j < NJ; ++j) w1[j] = 1.f;

        #pragma unroll 1
        for (int c = 0; c < NCLS; ++c) {
            unsigned up[NJ][8];
            float acc[KDO];
            #pragma unroll
            for (int d = 0; d < KDO; ++d) acc[d] = 0.f;
            sweep_class(Wt, c, xh, t, w1, up, acc);
            class_tail(c, false, true, 0.1f, t, lane, wave, par, up, acc,
                       blogL, red, outb);
            par ^= 1;
        }
    }

    // ================= it = 1, 2 ===========================================
    #pragma unroll 1
    for (int it = 1; it < NIT; ++it) {
        bool last = (it == NIT - 1);

        // softmax over classes per capsule (thread-private blog slots)
        float sm[NJ], sid[NJ];
        #pragma unroll
        for (int j = 0; j < NJ; ++j) {
            int ii = t + TPB * j;
            if (ii < NCAPS) {
                float bl[NCLS];
                #pragma unroll
                for (int c = 0; c < NCLS; ++c) bl[c] = blogL[ii * BPAD + c];
                float m = bl[0];
                #pragma unroll
                for (int c = 1; c < NCLS; ++c) m = fmaxf(m, bl[c]);
                float den = 0.f;
                #pragma unroll
                for (int c = 0; c < NCLS; ++c) den += __expf(bl[c] - m);
                sm[j]  = m;
                sid[j] = 1.f / den;
            }
        }

        #pragma unroll 1
        for (int c = 0; c < NCLS; ++c) {
            float wj[NJ];
            #pragma unroll
            for (int j = 0; j < NJ; ++j) {
                int ii = t + TPB * j;
                wj[j] = (ii < NCAPS) ? __expf(blogL[ii * BPAD + c] - sm[j]) * sid[j] : 0.f;
            }
            unsigned up[NJ][8];
            float acc[KDO];
            #pragma unroll
            for (int d = 0; d < KDO; ++d) acc[d] = 0.f;
            sweep_class(Wt, c, xh, t, wj, up, acc);
            class_tail(c, last, false, 1.f, t, lane, wave, par, up, acc,
                       blogL, red, outb);
            par ^= 1;
        }
    }
}

// ---- fallback (no workspace): round-1 fp32 kernel, proven correct ----
__global__ __launch_bounds__(256, 2)
void caps_routing_fb(const float* __restrict__ x, const float* __restrict__ W,
                     float* __restrict__ out)
{
    const int b    = blockIdx.x;
    const int t    = threadIdx.x;
    const int lane = t & 63;
    const int wave = t >> 6;
    __shared__ float v_prev[NCLS * KDO];
    __shared__ float redf[NCLS * 4 * KDO];
    float4 xr[5][2];
    const float4* x4 = reinterpret_cast<const float4*>(x + (size_t)b * NCAPS * 8);
    #pragma unroll
    for (int j = 0; j < 5; ++j) {
        int i = t + 256 * j;
        if (i < NCAPS) { xr[j][0] = x4[2 * i]; xr[j][1] = x4[2 * i + 1]; }
    }
    float blog[5][NCLS];
    #pragma unroll
    for (int j = 0; j < 5; ++j)
        #pragma unroll
        for (int c = 0; c < NCLS; ++c) blog[j][c] = 0.f;
    const float4* W4 = reinterpret_cast<const float4*>(W);
    for (int it = 0; it < NIT; ++it) {
        if (it > 0) {
            for (int c = 0; c < NCLS; ++c) {
                float vp[KDO];
                #pragma unroll
                for (int d = 0; d < KDO; ++d) vp[d] = v_prev[c * KDO + d];
                #pragma unroll
                for (int j = 0; j < 5; ++j) {
                    int i = t + 256 * j;
                    if (i < NCAPS) {
                        size_t wb = (size_t)(c * NCAPS + i) * 32;
                        float a = 0.f;
                        #pragma unroll
                        for (int d = 0; d < KDO; ++d) {
                            float4 w0 = W4[wb + 2 * d]; float4 w1 = W4[wb + 2 * d + 1];
                            float u = w0.x*xr[j][0].x + w0.y*xr[j][0].y + w0.z*xr[j][0].z
                                    + w0.w*xr[j][0].w + w1.x*xr[j][1].x + w1.y*xr[j][1].y
                                    + w1.z*xr[j][1].z + w1.w*xr[j][1].w;
                            a += u * vp[d];
                        }
                        blog[j][c] += a;
                    }
                }
            }
        }
        float sm[5], sid[5];
        #pragma unroll
        for (int j = 0; j < 5; ++j) {
            int i = t + 256 * j;
            if (i < NCAPS) {
                float m = blog[j][0];
                #pragma unroll
                for (int c = 1; c < NCLS; ++c) m = fmaxf(m, blog[j][c]);
                float den = 0.f;
                #pragma unroll
                for (int c = 0; c < NCLS; ++c) den += __expf(blog[j][c] - m);
                sm[j] = m; sid[j] = 1.f / den;
            }
        }
        for (int c = 0; c < NCLS; ++c) {
            float acc[KDO];
            #pragma unroll
            for (int d = 0; d < KDO; ++d) acc[d] = 0.f;
            #pragma unroll
            for (int j = 0; j < 5; ++j) {
                int i = t + 256 * j;
                if (i < NCAPS) {
                    float w = __expf(blog[j][c] - sm[j]) * sid[j];
                    size_t wb = (size_t)(c * NCAPS + i) * 32;
                    #pragma unroll
                    for (int d = 0; d < KDO; ++d) {
                        float4 w0 = W4[wb + 2 * d]; float4 w1 = W4[wb + 2 * d + 1];
                        float u = w0.x*xr[j][0].x + w0.y*xr[j][0].y + w0.z*xr[j][0].z
                                + w0.w*xr[j][0].w + w1.x*xr[j][1].x + w1.y*xr[j][1].y
                                + w1.z*xr[j][1].z + w1.w*xr[j][1].w;
                        acc[d] += w * u;
                    }
                }
            }
            #pragma unroll
            for (int d = 0; d < KDO; ++d) {
                float v = acc[d];
                v += __shfl_xor(v, 32, 64); v += __shfl_xor(v, 16, 64);
                v += __shfl_xor(v,  8, 64); v += __shfl_xor(v,  4, 64);
                v += __shfl_xor(v,  2, 64); v += __shfl_xor(v,  1, 64);
                if (lane == 0) redf[(c * 4 + wave) * KDO + d] = v;
            }
        }
        __syncthreads();
        if (t < NCLS * KDO) {
            int c = t >> 4, d = t & 15;
            float s = redf[(c*4+0)*KDO+d] + redf[(c*4+1)*KDO+d]
                    + redf[(c*4+2)*KDO+d] + redf[(c*4+3)*KDO+d];
            float nsq = s * s;
            nsq += __shfl_xor(nsq, 8, 16); nsq += __shfl_xor(nsq, 4, 16);
            nsq += __shfl_xor(nsq, 2, 16); nsq += __shfl_xor(nsq, 1, 16);
            float scale = sqrtf(nsq) / (1.f + nsq);
            float vv = s * scale;
            v_prev[t] = vv;
            if (it == NIT - 1) out[(size_t)b * NCLS * KDO + t] = vv;
        }
        __syncthreads();
    }
}

extern "C" void kernel_launch(void* const* d_in, const int* in_sizes, int n_in,
                              void* d_out, int out_size, void* d_ws, size_t ws_size,
                              hipStream_t stream) {
    const float* x = (const float*)d_in[0];              // [256, 1152, 8] fp32
    const float4* W4 = (const float4*)d_in[1];           // [10, 1152, 1, 16, 8] fp32
    float* out = (float*)d_out;                          // [256, 10, 1, 16] fp32
    (void)in_sizes; (void)n_in; (void)out_size;

    const int B = 256;
    const size_t wt_bytes = (size_t)NCLS * KDO * NCAPS * sizeof(u4);  // 2.95 MB
    if (ws_size >= wt_bytes) {
        u4* Wt = (u4*)d_ws;
        int total = NCLS * NCAPS * KDO;
        pack_W_f16<<<dim3((total + 255) / 256), dim3(256), 0, stream>>>(W4, Wt);
        caps_routing_v11<<<dim3(B), dim3(TPB), 0, stream>>>(Wt, x, out);
    } else {
        caps_routing_fb<<<dim3(B), dim3(256), 0, stream>>>(x, (const float*)d_in[1], out);
    }
}

// Round 12
// 270.445 us; speedup vs baseline: 1.6090x; 1.2844x over previous
//
#include <hip/hip_runtime.h>

// DigitCapsules dynamic routing. Round-12 design:
//  - Empirical law (R7/R8/R11): pass cost ~ wave-load-instruction count
//    (~75-110 cyc each, TLP-insensitive). 30 recompute passes x 295 KB W/CU
//    is the floor of the recompute design. Lever: bytes per pass.
//  - d_ws is ~268 MB (harness fillBuffer poison = 262144 KB). u_hat f16 for
//    the whole problem is 94 MB, and per (c,i) use u_hat is 32 B vs 256 B of
//    W. So: it0 computes u_hat from W (10 sweeps, unchanged R11 path) and
//    STORES it packed-f16 to ws (bits already in up[] for the agreement
//    step; 2 coalesced u4 stores per class-chunk). Iters 1-2 load u_hat
//    back (2 u4 loads vs 16 per class-chunk): 8x fewer bytes/instructions.
//    Same-launch write->read only; ws re-poison between launches harmless.
//  - Layout ut[b][c][h][i] (h = d-half): lane stride 16 B on store AND load.
//  - Everything else is the R11-proven skeleton: TPB=256 launch_bounds(256,1)
//    (cap 256, VGPR 108, zero spill), blog in LDS BPAD=11 (0 conflicts),
//    batched 16-row W loads, f16 Wt[c][d][i] + v_dot2_f32_f16, it0
//    softmax(0)=0.1 shortcut, parity-red 1-barrier class tail.

#define NCLS   10
#define NCAPS  1152
#define KDO    16
#define NIT    3
#define TPB    256
#define NJ     5            // j=0..3 all threads; j=4 only t<128
#define NWAVE  (TPB / 64)
#define BPAD   11

typedef _Float16 h2_t __attribute__((ext_vector_type(2)));
typedef unsigned u4 __attribute__((ext_vector_type(4)));

static __device__ __forceinline__ unsigned pack2h(float a, float b) {
    union { _Float16 h[2]; unsigned u; } p;
    p.h[0] = (_Float16)a;
    p.h[1] = (_Float16)b;
    return p.u;
}

static __device__ __forceinline__ float dot8h(u4 r, const unsigned* xh) {
    union { unsigned u; h2_t h; } w0, w1, w2, w3, a0, a1, a2, a3;
    w0.u = r.x; w1.u = r.y; w2.u = r.z; w3.u = r.w;
    a0.u = xh[0]; a1.u = xh[1]; a2.u = xh[2]; a3.u = xh[3];
#if __has_builtin(__builtin_amdgcn_fdot2)
    float acc = __builtin_amdgcn_fdot2(w0.h, a0.h, 0.f, false);
    acc = __builtin_amdgcn_fdot2(w1.h, a1.h, acc, false);
    acc = __builtin_amdgcn_fdot2(w2.h, a2.h, acc, false);
    acc = __builtin_amdgcn_fdot2(w3.h, a3.h, acc, false);
    return acc;
#else
    return (float)w0.h.x * (float)a0.h.x + (float)w0.h.y * (float)a0.h.y
         + (float)w1.h.x * (float)a1.h.x + (float)w1.h.y * (float)a1.h.y
         + (float)w2.h.x * (float)a2.h.x + (float)w2.h.y * (float)a2.h.y
         + (float)w3.h.x * (float)a3.h.x + (float)w3.h.y * (float)a3.h.y;
#endif
}

static __device__ __forceinline__ float dot2h(unsigned a, unsigned b, float acc) {
    union { unsigned u; h2_t h; } pa, pb;
    pa.u = a; pb.u = b;
#if __has_builtin(__builtin_amdgcn_fdot2)
    return __builtin_amdgcn_fdot2(pa.h, pb.h, acc, false);
#else
    return acc + (float)pa.h.x * (float)pb.h.x + (float)pa.h.y * (float)pb.h.y;
#endif
}

// Wt[c][d][i] : u4 holding f16 W[c,i,0,d,k] for k=0..7
__global__ __launch_bounds__(256)
void pack_W_f16(const float4* __restrict__ W4, u4* __restrict__ Wt) {
    int tid = blockIdx.x * blockDim.x + threadIdx.x;   // (c*NCAPS+i)*KDO + d
    if (tid >= NCLS * NCAPS * KDO) return;
    int d = tid & 15;
    int rest = tid >> 4;
    int i = rest % NCAPS;
    int c = rest / NCAPS;
    float4 a = W4[2 * tid];
    float4 b = W4[2 * tid + 1];
    u4 o;
    o.x = pack2h(a.x, a.y);
    o.y = pack2h(a.z, a.w);
    o.z = pack2h(b.x, b.y);
    o.w = pack2h(b.z, b.w);
    Wt[(size_t)(c * KDO + d) * NCAPS + i] = o;
}

// ---- one class-sweep: BATCHED 16-row load, then dots. up = packed u_hat. ----
static __device__ __forceinline__ void sweep_class(
        const u4* __restrict__ Wt, int c, const unsigned (&xh)[NJ][4],
        int t, const float (&wj)[NJ], unsigned (&up)[NJ][8], float (&acc)[KDO])
{
    #pragma unroll
    for (int j = 0; j < NJ; ++j) {
        int ii = t + TPB * j;
        if (ii < NCAPS) {
            const u4* base = Wt + (size_t)c * KDO * NCAPS + ii;
            u4 r[KDO];                           // all 16 loads in flight
            #pragma unroll
            for (int d = 0; d < KDO; ++d)
                r[d] = __builtin_nontemporal_load(base + (size_t)d * NCAPS);
            #pragma unroll
            for (int dp = 0; dp < 8; ++dp) {
                float u0 = dot8h(r[2 * dp],     xh[j]);
                float u1 = dot8h(r[2 * dp + 1], xh[j]);
                acc[2 * dp]     += wj[j] * u0;
                acc[2 * dp + 1] += wj[j] * u1;
                up[j][dp] = pack2h(u0, u1);
            }
        }
    }
}

// ---- weighted accumulate from cached packed-f16 u ----
static __device__ __forceinline__ void acc_from_u(
        const unsigned (&up)[NJ][8], const float (&wj)[NJ], int t, float (&acc)[KDO])
{
    #pragma unroll
    for (int j = 0; j < NJ; ++j) {
        int ii = t + TPB * j;
        if (ii < NCAPS) {
            #pragma unroll
            for (int dp = 0; dp < 8; ++dp) {
                union { unsigned u; h2_t h; } p; p.u = up[j][dp];
                acc[2 * dp]     += wj[j] * (float)p.h.x;
                acc[2 * dp + 1] += wj[j] * (float)p.h.y;
            }
        }
    }
}

// ---- reduce + squash + (out-write | agreement). ONE barrier, red parity. ----
static __device__ __forceinline__ void class_tail(
        int c, bool last, bool first, float s_scale,
        int t, int lane, int wave, int par,
        const unsigned (&up)[NJ][8], float (&acc)[KDO],
        float* __restrict__ blogL, float (*__restrict__ red)[NWAVE * KDO],
        float* __restrict__ outb)
{
    #pragma unroll
    for (int d = 0; d < KDO; ++d) {
        float v = acc[d];
        v += __shfl_xor(v, 32, 64);
        v += __shfl_xor(v, 16, 64);
        v += __shfl_xor(v,  8, 64);
        v += __shfl_xor(v,  4, 64);
        v += __shfl_xor(v,  2, 64);
        v += __shfl_xor(v,  1, 64);
        if (lane == 0) red[par][wave * KDO + d] = v;
    }
    __syncthreads();

    // every wave redundantly computes s, v (lanes: d = lane&15, 4 replicas)
    int dl = lane & 15;
    float s = 0.f;
    #pragma unroll
    for (int w = 0; w < NWAVE; ++w) s += red[par][w * KDO + dl];
    s *= s_scale;
    float nsq = s * s;
    nsq += __shfl_xor(nsq, 8, 16);
    nsq += __shfl_xor(nsq, 4, 16);
    nsq += __shfl_xor(nsq, 2, 16);
    nsq += __shfl_xor(nsq, 1, 16);
    float sc = sqrtf(nsq) / (1.f + nsq);       // (nsq/(1+nsq))/sqrt(nsq)
    float vv = s * sc;

    if (last) {
        if (wave == 0 && lane < 16)
            outb[c * KDO + lane] = vv;
    } else {
        unsigned vp[8];
        #pragma unroll
        for (int dp = 0; dp < 8; ++dp) {
            float a = __shfl(vv, (lane & 48) + 2 * dp, 64);
            float b = __shfl(vv, (lane & 48) + 2 * dp + 1, 64);
            vp[dp] = pack2h(a, b);
        }
        #pragma unroll
        for (int j = 0; j < NJ; ++j) {
            int ii = t + TPB * j;
            if (ii < NCAPS) {
                float a = 0.f;
                #pragma unroll
                for (int dp = 0; dp < 8; ++dp) a = dot2h(up[j][dp], vp[dp], a);
                if (first) blogL[ii * BPAD + c] = a;     // it0: first write, no init
                else       blogL[ii * BPAD + c] += a;
            }
        }
    }
}

__global__ __launch_bounds__(TPB, 1)          // cap 256 VGPR at TPB=256 (measured)
void caps_routing_v12(const u4* __restrict__ Wt,    // [C][KDO][I] f16x8
                      u4* __restrict__ ut,          // [B][C][2][I] u_hat f16x8
                      const float* __restrict__ x,  // [B, I, 8]
                      float* __restrict__ out)      // [B, C, 1, KDO]
{
    const int b    = blockIdx.x;
    const int t    = threadIdx.x;
    const int lane = t & 63;
    const int wave = t >> 6;

    __shared__ float blogL[NCAPS * BPAD];               // 50688 B
    __shared__ float red[2][NWAVE * KDO];               // 512 B

    // ---- x[b, ii, :] packed f16 in registers ----
    unsigned xh[NJ][4];
    const float4* x4 = reinterpret_cast<const float4*>(x) + (size_t)b * NCAPS * 2;
    #pragma unroll
    for (int j = 0; j < NJ; ++j) {
        int ii = t + TPB * j;
        if (ii < NCAPS) {
            float4 x0 = x4[2 * ii];
            float4 x1 = x4[2 * ii + 1];
            xh[j][0] = pack2h(x0.x, x0.y);
            xh[j][1] = pack2h(x0.z, x0.w);
            xh[j][2] = pack2h(x1.x, x1.y);
            xh[j][3] = pack2h(x1.z, x1.w);
        }
    }

    float* outb = out + (size_t)b * NCLS * KDO;
    u4* utb = ut + (size_t)b * NCLS * 2 * NCAPS;
    int par = 0;

    // ===== it = 0 : softmax(0)=0.1 -> unweighted, scale 0.1; store u_hat ====
    {
        float w1[NJ];
        #pragma unroll
        for (int j = 0; j < NJ; ++j) w1[j] = 1.f;

        #pragma unroll 1
        for (int c = 0; c < NCLS; ++c) {
            unsigned up[NJ][8];
            float acc[KDO];
            #pragma unroll
            for (int d = 0; d < KDO; ++d) acc[d] = 0.f;
            sweep_class(Wt, c, xh, t, w1, up, acc);

            // store u_hat packed f16 (coalesced: lane stride 16 B on ii)
            #pragma unroll
            for (int j = 0; j < NJ; ++j) {
                int ii = t + TPB * j;
                if (ii < NCAPS) {
                    u4 h0, h1;
                    h0.x = up[j][0]; h0.y = up[j][1]; h0.z = up[j][2]; h0.w = up[j][3];
                    h1.x = up[j][4]; h1.y = up[j][5]; h1.z = up[j][6]; h1.w = up[j][7];
                    utb[((size_t)c * 2 + 0) * NCAPS + ii] = h0;
                    utb[((size_t)c * 2 + 1) * NCAPS + ii] = h1;
                }
            }

            class_tail(c, false, true, 0.1f, t, lane, wave, par, up, acc,
                       blogL, red, outb);
            par ^= 1;
        }
    }

    // ===== it = 1, 2 : u_hat from ws cache (2 loads vs 16 per chunk) ========
    #pragma unroll 1
    for (int it = 1; it < NIT; ++it) {
        bool last = (it == NIT - 1);

        // softmax over classes per capsule (thread-private blog slots)
        float sm[NJ], sid[NJ];
        #pragma unroll
        for (int j = 0; j < NJ; ++j) {
            int ii = t + TPB * j;
            if (ii < NCAPS) {
                float bl[NCLS];
                #pragma unroll
                for (int c = 0; c < NCLS; ++c) bl[c] = blogL[ii * BPAD + c];
                float m = bl[0];
                #pragma unroll
                for (int c = 1; c < NCLS; ++c) m = fmaxf(m, bl[c]);
                float den = 0.f;
                #pragma unroll
                for (int c = 0; c < NCLS; ++c) den += __expf(bl[c] - m);
                sm[j]  = m;
                sid[j] = 1.f / den;
            }
        }

        #pragma unroll 1
        for (int c = 0; c < NCLS; ++c) {
            unsigned up[NJ][8];
            #pragma unroll
            for (int j = 0; j < NJ; ++j) {
                int ii = t + TPB * j;
                if (ii < NCAPS) {
                    u4 h0 = utb[((size_t)c * 2 + 0) * NCAPS + ii];
                    u4 h1 = utb[((size_t)c * 2 + 1) * NCAPS + ii];
                    up[j][0] = h0.x; up[j][1] = h0.y; up[j][2] = h0.z; up[j][3] = h0.w;
                    up[j][4] = h1.x; up[j][5] = h1.y; up[j][6] = h1.z; up[j][7] = h1.w;
                }
            }
            float wj[NJ];
            #pragma unroll
            for (int j = 0; j < NJ; ++j) {
                int ii = t + TPB * j;
                wj[j] = (ii < NCAPS) ? __expf(blogL[ii * BPAD + c] - sm[j]) * sid[j] : 0.f;
            }
            float acc[KDO];
            #pragma unroll
            for (int d = 0; d < KDO; ++d) acc[d] = 0.f;
            acc_from_u(up, wj, t, acc);
            class_tail(c, last, false, 1.f, t, lane, wave, par, up, acc,
                       blogL, red, outb);
            par ^= 1;
        }
    }
}

// ---- fallback (no/small workspace): round-1 fp32 kernel, proven correct ----
__global__ __launch_bounds__(256, 2)
void caps_routing_fb(const float* __restrict__ x, const float* __restrict__ W,
                     float* __restrict__ out)
{
    const int b    = blockIdx.x;
    const int t    = threadIdx.x;
    const int lane = t & 63;
    const int wave = t >> 6;
    __shared__ float v_prev[NCLS * KDO];
    __shared__ float redf[NCLS * 4 * KDO];
    float4 xr[5][2];
    const float4* x4 = reinterpret_cast<const float4*>(x + (size_t)b * NCAPS * 8);
    #pragma unroll
    for (int j = 0; j < 5; ++j) {
        int i = t + 256 * j;
        if (i < NCAPS) { xr[j][0] = x4[2 * i]; xr[j][1] = x4[2 * i + 1]; }
    }
    float blog[5][NCLS];
    #pragma unroll
    for (int j = 0; j < 5; ++j)
        #pragma unroll
        for (int c = 0; c < NCLS; ++c) blog[j][c] = 0.f;
    const float4* W4 = reinterpret_cast<const float4*>(W);
    for (int it = 0; it < NIT; ++it) {
        if (it > 0) {
            for (int c = 0; c < NCLS; ++c) {
                float vp[KDO];
                #pragma unroll
                for (int d = 0; d < KDO; ++d) vp[d] = v_prev[c * KDO + d];
                #pragma unroll
                for (int j = 0; j < 5; ++j) {
                    int i = t + 256 * j;
                    if (i < NCAPS) {
                        size_t wb = (size_t)(c * NCAPS + i) * 32;
                        float a = 0.f;
                        #pragma unroll
                        for (int d = 0; d < KDO; ++d) {
                            float4 w0 = W4[wb + 2 * d]; float4 w1 = W4[wb + 2 * d + 1];
                            float u = w0.x*xr[j][0].x + w0.y*xr[j][0].y + w0.z*xr[j][0].z
                                    + w0.w*xr[j][0].w + w1.x*xr[j][1].x + w1.y*xr[j][1].y
                                    + w1.z*xr[j][1].z + w1.w*xr[j][1].w;
                            a += u * vp[d];
                        }
                        blog[j][c] += a;
                    }
                }
            }
        }
        float sm[5], sid[5];
        #pragma unroll
        for (int j = 0; j < 5; ++j) {
            int i = t + 256 * j;
            if (i < NCAPS) {
                float m = blog[j][0];
                #pragma unroll
                for (int c = 1; c < NCLS; ++c) m = fmaxf(m, blog[j][c]);
                float den = 0.f;
                #pragma unroll
                for (int c = 0; c < NCLS; ++c) den += __expf(blog[j][c] - m);
                sm[j] = m; sid[j] = 1.f / den;
            }
        }
        for (int c = 0; c < NCLS; ++c) {
            float acc[KDO];
            #pragma unroll
            for (int d = 0; d < KDO; ++d) acc[d] = 0.f;
            #pragma unroll
            for (int j = 0; j < 5; ++j) {
                int i = t + 256 * j;
                if (i < NCAPS) {
                    float w = __expf(blog[j][c] - sm[j]) * sid[j];
                    size_t wb = (size_t)(c * NCAPS + i) * 32;
                    #pragma unroll
                    for (int d = 0; d < KDO; ++d) {
                        float4 w0 = W4[wb + 2 * d]; float4 w1 = W4[wb + 2 * d + 1];
                        float u = w0.x*xr[j][0].x + w0.y*xr[j][0].y + w0.z*xr[j][0].z
                                + w0.w*xr[j][0].w + w1.x*xr[j][1].x + w1.y*xr[j][1].y
                                + w1.z*xr[j][1].z + w1.w*xr[j][1].w;
                        acc[d] += w * u;
                    }
                }
            }
            #pragma unroll
            for (int d = 0; d < KDO; ++d) {
                float v = acc[d];
                v += __shfl_xor(v, 32, 64); v += __shfl_xor(v, 16, 64);
                v += __shfl_xor(v,  8, 64); v += __shfl_xor(v,  4, 64);
                v += __shfl_xor(v,  2, 64); v += __shfl_xor(v,  1, 64);
                if (lane == 0) redf[(c * 4 + wave) * KDO + d] = v;
            }
        }
        __syncthreads();
        if (t < NCLS * KDO) {
            int c = t >> 4, d = t & 15;
            float s = redf[(c*4+0)*KDO+d] + redf[(c*4+1)*KDO+d]
                    + redf[(c*4+2)*KDO+d] + redf[(c*4+3)*KDO+d];
            float nsq = s * s;
            nsq += __shfl_xor(nsq, 8, 16); nsq += __shfl_xor(nsq, 4, 16);
            nsq += __shfl_xor(nsq, 2, 16); nsq += __shfl_xor(nsq, 1, 16);
            float scale = sqrtf(nsq) / (1.f + nsq);
            float vv = s * scale;
            v_prev[t] = vv;
            if (it == NIT - 1) out[(size_t)b * NCLS * KDO + t] = vv;
        }
        __syncthreads();
    }
}

extern "C" void kernel_launch(void* const* d_in, const int* in_sizes, int n_in,
                              void* d_out, int out_size, void* d_ws, size_t ws_size,
                              hipStream_t stream) {
    const float* x = (const float*)d_in[0];              // [256, 1152, 8] fp32
    const float4* W4 = (const float4*)d_in[1];           // [10, 1152, 1, 16, 8] fp32
    float* out = (float*)d_out;                          // [256, 10, 1, 16] fp32
    (void)in_sizes; (void)n_in; (void)out_size;

    const int B = 256;
    const size_t wt_bytes = (size_t)NCLS * KDO * NCAPS * sizeof(u4);        // 2.95 MB
    const size_t ut_bytes = (size_t)B * NCLS * 2 * NCAPS * sizeof(u4);      // 94.4 MB
    if (ws_size >= wt_bytes + ut_bytes) {
        u4* Wt = (u4*)d_ws;
        u4* ut = (u4*)((char*)d_ws + wt_bytes);
        int total = NCLS * NCAPS * KDO;
        pack_W_f16<<<dim3((total + 255) / 256), dim3(256), 0, stream>>>(W4, Wt);
        caps_routing_v12<<<dim3(B), dim3(TPB), 0, stream>>>(Wt, ut, x, out);
    } else {
        caps_routing_fb<<<dim3(B), dim3(256), 0, stream>>>(x, (const float*)d_in[1], out);
    }
}